// Round 6
// baseline (103.852 us; speedup 1.0000x reference)
//
#include <hip/hip_runtime.h>
#include <math.h>

#define Bq 8
#define Qq 256
#define Tt 128
#define Pp 100
#define Mm 512
#define Nn 1024  // B*T

// Block-wide sum over 256 threads (4 waves of 64). Result broadcast to all threads.
__device__ __forceinline__ float breduce256(float v, float* red) {
    #pragma unroll
    for (int off = 32; off > 0; off >>= 1) v += __shfl_down(v, off, 64);
    __syncthreads();                         // protect red[] reuse across calls
    if ((threadIdx.x & 63) == 0) red[threadIdx.x >> 6] = v;
    __syncthreads();
    return red[0] + red[1] + red[2] + red[3];
}

// One block per patch, fused single-pass chamfer (each distance computed once).
// Thread (g = tid&7, c = tid>>3) holds src points p = 16g..16g+15 in REGISTERS
// and sweeps the 16 tgt points of m-chunk c:
//   - per-p running min in registers, merged at loop end via 16 LDS atomicMin
//   - per-m min over p via one LDS atomicMin per iteration
// s_tgt / s_amin use an XOR swizzle (r ^= c&7) so the 64 lanes' b128 reads hit
// distinct bank quads; the final sum over s_amin is permutation-invariant so
// the swizzle needs no inverse. src padded to 128 pts with 5e18 sentinels
// (d^2 ~ 7.5e37, finite, never wins a min) -> zero hot-loop predication.
// The LAST block to finish (device-scope atomic counter) runs the
// classification losses inline -> no second dispatch.
__global__ __launch_bounds__(256) void fused_kernel(
    const float* __restrict__ logits,     // [B,Q,2]
    const float* __restrict__ pred_pts,   // [B,Q,P,3]
    const float* __restrict__ tgt_pts,    // [B,T,M,3]
    const int*   __restrict__ src_idx,    // [B,T]
    float*       __restrict__ per_patch,  // ws: [N]
    unsigned*    __restrict__ done_ctr,   // ws+4096, zeroed per launch
    float*       __restrict__ out)        // [5]
{
    __shared__ float4   s_tgt[Mm];        // 8 KB (swizzled)
    __shared__ float4   s_src[128];       // 2 KB (padded)
    __shared__ unsigned s_amin[Mm];       // 2 KB: per-m min over p (swizzled)
    __shared__ unsigned s_bmin[128];      // 0.5 KB: per-p min over m
    __shared__ float    red[4];
    __shared__ unsigned s_lastflag;
    const int n   = blockIdx.x;
    const int tid = threadIdx.x;
    const int b   = n >> 7;               // n / T
    const int q   = src_idx[n];
    const float* sp = pred_pts + (size_t)(b * Qq + q) * (Pp * 3);
    const float* tp = tgt_pts  + (size_t)n * (Mm * 3);

    // Stage tgt (swizzled): 768 float2; thread repacks 2 points.
    {
        const float2* tp2 = (const float2*)tp;
        const float2 a = tp2[3*tid], c2 = tp2[3*tid+1], e = tp2[3*tid+2];
        const int m0 = 2*tid, m1 = 2*tid + 1;
        const int p0 = (m0 & ~15) | ((m0 & 15) ^ ((m0 >> 4) & 7));
        const int p1 = (m1 & ~15) | ((m1 & 15) ^ ((m1 >> 4) & 7));
        s_tgt[p0] = make_float4(a.x, a.y, c2.x, 0.f);
        s_tgt[p1] = make_float4(c2.y, e.x, e.y, 0.f);
    }
    // Stage src: threads 0..49 repack 2 points each; 100..127 write sentinels.
    if (tid < 50) {
        const float2* sp2 = (const float2*)sp;
        const float2 a = sp2[3*tid], c2 = sp2[3*tid+1], e = sp2[3*tid+2];
        s_src[2*tid]   = make_float4(a.x, a.y, c2.x, 0.f);
        s_src[2*tid+1] = make_float4(c2.y, e.x, e.y, 0.f);
    } else if (tid >= 100 && tid < 128) {
        s_src[tid] = make_float4(5e18f, 5e18f, 5e18f, 0.f);
    }
    *(uint2*)&s_amin[2*tid] = make_uint2(0x7f7fffffu, 0x7f7fffffu);
    if (tid < 128) s_bmin[tid] = 0x7f7fffffu;
    __syncthreads();

    const int g     = tid & 7;            // src sub-block (16 points)
    const int c     = tid >> 3;           // m-chunk 0..31 (16 m's)
    const int mswz  = c & 7;
    const int mbase = c << 4;
    float4 S[16];
    #pragma unroll
    for (int k = 0; k < 16; ++k) S[k] = s_src[16*g + k];
    float mn[16];
    #pragma unroll
    for (int k = 0; k < 16; ++k) mn[k] = 3.4e38f;

    #pragma unroll
    for (int j = 0; j < 16; ++j) {
        const int idx = mbase + (((j + g) & 15) ^ mswz);  // swizzled slot
        const float4 t = s_tgt[idx];
        float pmA = 3.4e38f, pmB = 3.4e38f, pmC = 3.4e38f, pmD = 3.4e38f;
        #pragma unroll
        for (int k = 0; k < 16; k += 4) {
            float dx, dy, dz, d;
            dx = S[k].x-t.x;   dy = S[k].y-t.y;   dz = S[k].z-t.z;
            d = fmaf(dx,dx,fmaf(dy,dy,dz*dz)); mn[k]   = fminf(mn[k],   d); pmA = fminf(pmA, d);
            dx = S[k+1].x-t.x; dy = S[k+1].y-t.y; dz = S[k+1].z-t.z;
            d = fmaf(dx,dx,fmaf(dy,dy,dz*dz)); mn[k+1] = fminf(mn[k+1], d); pmB = fminf(pmB, d);
            dx = S[k+2].x-t.x; dy = S[k+2].y-t.y; dz = S[k+2].z-t.z;
            d = fmaf(dx,dx,fmaf(dy,dy,dz*dz)); mn[k+2] = fminf(mn[k+2], d); pmC = fminf(pmC, d);
            dx = S[k+3].x-t.x; dy = S[k+3].y-t.y; dz = S[k+3].z-t.z;
            d = fmaf(dx,dx,fmaf(dy,dy,dz*dz)); mn[k+3] = fminf(mn[k+3], d); pmD = fminf(pmD, d);
        }
        const float pm = fminf(fminf(pmA, pmB), fminf(pmC, pmD));
        atomicMin(&s_amin[idx], __float_as_uint(pm));  // nonneg: uint cmp == float cmp
    }
    #pragma unroll
    for (int k = 0; k < 16; ++k)
        atomicMin(&s_bmin[16*g + k], __float_as_uint(mn[k]));
    __syncthreads();

    float contrib;
    {   // Pass A: mean over m of min_p (sum over swizzled slots = same sum).
        const uint2 u = *(const uint2*)&s_amin[2*tid];
        contrib = (__uint_as_float(u.x) + __uint_as_float(u.y)) * (1.0f / Mm);
    }
    // Pass B: threads 0..99 own one real p each.
    if (tid < Pp) contrib += 0.2f * __uint_as_float(s_bmin[tid]) * (1.0f / Pp);

    const float tot = breduce256(contrib, red);
    if (tid == 0) {
        per_patch[n] = tot * (1.0f / 1.2f);
        __threadfence();                                   // publish before count
        s_lastflag = (atomicAdd(done_ctr, 1u) == (unsigned)(Nn - 1));
    }
    __syncthreads();
    if (!s_lastflag) return;

    // ---------------- consumer tail: classification losses (one block) -------
    __shared__ unsigned char matched[Bq * Qq];
    __shared__ int s_card[Bq];
    for (int i = tid; i < Bq * Qq; i += 256) matched[i] = 0;
    if (tid < Bq) s_card[tid] = 0;
    __syncthreads();
    for (int i = tid; i < Nn; i += 256) matched[(i >> 7) * Qq + src_idx[i]] = 1;
    __syncthreads();

    float sum_nll = 0.f, sum_wt = 0.f, cnt_ov = 0.f;
    #pragma unroll
    for (int k = 0; k < 8; ++k) {                // k == batch b (Q == 256)
        const int i = tid + (k << 8);
        const float2 l = ((const float2*)logits)[i];
        const int mt = matched[i];
        const float mx  = fmaxf(l.x, l.y);
        const float lse = mx + logf(expf(l.x - mx) + expf(l.y - mx));
        sum_nll += (mt ? 1.0f : 0.1f) * (lse - (mt ? l.x : l.y));
        sum_wt  += mt ? 1.0f : 0.1f;
        const int pred0 = (l.x >= l.y) ? 1 : 0;  // argmax==0 (tie -> first)
        cnt_ov += (pred0 == mt) ? 1.f : 0.f;
        const unsigned long long bal = __ballot(pred0);
        if ((tid & 63) == 0) atomicAdd(&s_card[k], (int)__popcll(bal));
    }
    float cnt_va = 0.f, gsum = 0.f;
    const volatile float* vpp = per_patch;       // cross-XCD: bypass reg caching
    for (int i = tid; i < Nn; i += 256) {
        const float2 l = ((const float2*)logits)[(i >> 7) * Qq + src_idx[i]];
        cnt_va += (l.x >= l.y) ? 1.f : 0.f;
        gsum   += vpp[i];
    }

    const float t_nll = breduce256(sum_nll, red);
    const float t_wt  = breduce256(sum_wt,  red);
    const float t_ov  = breduce256(cnt_ov,  red);
    const float t_va  = breduce256(cnt_va,  red);
    const float t_gs  = breduce256(gsum,    red);

    if (tid == 0) {
        float cerr = 0.f;
        for (int bb = 0; bb < Bq; ++bb) cerr += fabsf((float)s_card[bb] - (float)Tt);
        out[0] = t_nll / t_wt;
        out[1] = 100.f * t_va / (float)Nn;
        out[2] = 100.f * t_ov / (float)(Bq * Qq);
        out[3] = cerr / (float)Bq;
        out[4] = t_gs / (float)Nn;
    }
}

extern "C" void kernel_launch(void* const* d_in, const int* in_sizes, int n_in,
                              void* d_out, int out_size, void* d_ws, size_t ws_size,
                              hipStream_t stream) {
    const float* logits   = (const float*)d_in[0];  // [B,Q,2]
    const float* pred_pts = (const float*)d_in[1];  // [B,Q,P,3]
    const float* tgt_pts  = (const float*)d_in[2];  // [B,T,M,3]
    const int*   src_idx  = (const int*)  d_in[3];  // [B,T]
    float* out       = (float*)d_out;               // 5 scalars
    float* per_patch = (float*)d_ws;                // [1024] floats
    unsigned* ctr    = (unsigned*)((char*)d_ws + 4096);

    hipMemsetAsync(ctr, 0, sizeof(unsigned), stream);   // graph-capture legal
    fused_kernel<<<Nn, 256, 0, stream>>>(logits, pred_pts, tgt_pts, src_idx,
                                         per_patch, ctr, out);
}

// Round 9
// 101.280 us; speedup vs baseline: 1.0254x; 1.0254x over previous
//
#include <hip/hip_runtime.h>
#include <math.h>

#define Bq 8
#define Qq 256
#define Tt 128
#define Pp 100
#define Mm 512
#define Nn 1024  // B*T

// Block-wide sum over 256 threads (4 waves of 64). Result broadcast to all threads.
__device__ __forceinline__ float breduce256(float v, float* red) {
    #pragma unroll
    for (int off = 32; off > 0; off >>= 1) v += __shfl_down(v, off, 64);
    __syncthreads();                         // protect red[] reuse across calls
    if ((threadIdx.x & 63) == 0) red[threadIdx.x >> 6] = v;
    __syncthreads();
    return red[0] + red[1] + red[2] + red[3];
}

__device__ __forceinline__ float dist2(float sx, float sy, float sz, float4 t) {
    const float dx = sx - t.x, dy = sy - t.y, dz = sz - t.z;
    return fmaf(dx, dx, fmaf(dy, dy, dz * dz));
}

// One block per patch, fused single-pass chamfer (each distance computed once).
// Thread (g = tid&15, c = tid>>4) holds src points p = 8g..8g+7 as 24 NAMED
// float registers (launch_bounds(256,4) caps occupancy at the grid's actual
// 4 waves/EU -> VGPR budget 128, so the compiler keeps them resident; r6's
// VGPR=52 remat disaster came from the occupancy heuristic) and sweeps the
// 32 tgt points of m-chunk c:
//   - per-p running min in 8 named registers, merged via 8 LDS atomicMin
//   - per-m min over p via one LDS atomicMin per iteration
// Rotation (j + g + 8*(c&3))&31 gives distinct addresses per lane, <=2-way
// bank aliasing on both the b128 read and the atomic (2-way is free, m136).
// src padded to 128 pts with 5e18 sentinels (d^2 ~ 7.5e37, finite, never wins
// a min) -> zero hot-loop predication. The LAST block to finish (device-scope
// atomic counter) runs the classification losses inline -> single dispatch.
__global__ __launch_bounds__(256, 4) void fused_kernel(
    const float* __restrict__ logits,     // [B,Q,2]
    const float* __restrict__ pred_pts,   // [B,Q,P,3]
    const float* __restrict__ tgt_pts,    // [B,T,M,3]
    const int*   __restrict__ src_idx,    // [B,T]
    float*       __restrict__ per_patch,  // ws: [N]
    unsigned*    __restrict__ done_ctr,   // ws+4096, zeroed per launch
    float*       __restrict__ out)        // [5]
{
    __shared__ float4   s_tgt[Mm];        // 8 KB
    __shared__ float4   s_src[128];       // 2 KB (padded)
    __shared__ unsigned s_amin[Mm];       // 2 KB: per-m min over p
    __shared__ unsigned s_bmin[128];      // 0.5 KB: per-p min over m
    __shared__ float    red[4];
    __shared__ unsigned s_lastflag;
    const int n   = blockIdx.x;
    const int tid = threadIdx.x;
    const int b   = n >> 7;               // n / T
    const int q   = src_idx[n];
    const float* sp = pred_pts + (size_t)(b * Qq + q) * (Pp * 3);
    const float* tp = tgt_pts  + (size_t)n * (Mm * 3);

    // Stage tgt: 512 pts x 3 floats = 768 float2; thread repacks 2 points.
    {
        const float2* tp2 = (const float2*)tp;
        const float2 a = tp2[3*tid], c2 = tp2[3*tid+1], e = tp2[3*tid+2];
        s_tgt[2*tid]   = make_float4(a.x, a.y, c2.x, 0.f);
        s_tgt[2*tid+1] = make_float4(c2.y, e.x, e.y, 0.f);
    }
    // Stage src: threads 0..49 repack 2 points each; 100..127 write sentinels.
    if (tid < 50) {
        const float2* sp2 = (const float2*)sp;
        const float2 a = sp2[3*tid], c2 = sp2[3*tid+1], e = sp2[3*tid+2];
        s_src[2*tid]   = make_float4(a.x, a.y, c2.x, 0.f);
        s_src[2*tid+1] = make_float4(c2.y, e.x, e.y, 0.f);
    } else if (tid >= 100 && tid < 128) {
        s_src[tid] = make_float4(5e18f, 5e18f, 5e18f, 0.f);
    }
    *(uint2*)&s_amin[2*tid] = make_uint2(0x7f7fffffu, 0x7f7fffffu);
    if (tid < 128) s_bmin[tid] = 0x7f7fffffu;
    __syncthreads();

    const int g     = tid & 15;           // src sub-block (8 points)
    const int c     = tid >> 4;           // m-chunk 0..15 (32 m's)
    const int mbase = c << 5;
    const int rot   = (g + ((c & 3) << 3)) & 31;

    // 8 src points as 24 named scalars (forced register residency).
    const float4 q0 = s_src[8*g+0], q1 = s_src[8*g+1], q2 = s_src[8*g+2], q3 = s_src[8*g+3];
    const float4 q4 = s_src[8*g+4], q5 = s_src[8*g+5], q6 = s_src[8*g+6], q7 = s_src[8*g+7];
    const float s0x=q0.x, s0y=q0.y, s0z=q0.z;
    const float s1x=q1.x, s1y=q1.y, s1z=q1.z;
    const float s2x=q2.x, s2y=q2.y, s2z=q2.z;
    const float s3x=q3.x, s3y=q3.y, s3z=q3.z;
    const float s4x=q4.x, s4y=q4.y, s4z=q4.z;
    const float s5x=q5.x, s5y=q5.y, s5z=q5.z;
    const float s6x=q6.x, s6y=q6.y, s6z=q6.z;
    const float s7x=q7.x, s7y=q7.y, s7z=q7.z;
    float mn0 = 3.4e38f, mn1 = 3.4e38f, mn2 = 3.4e38f, mn3 = 3.4e38f;
    float mn4 = 3.4e38f, mn5 = 3.4e38f, mn6 = 3.4e38f, mn7 = 3.4e38f;

    #pragma unroll 8
    for (int j = 0; j < 32; ++j) {
        const int m = mbase + ((j + rot) & 31);   // distinct addr per lane
        const float4 t = s_tgt[m];
        const float d0 = dist2(s0x,s0y,s0z,t); mn0 = fminf(mn0,d0);
        const float d1 = dist2(s1x,s1y,s1z,t); mn1 = fminf(mn1,d1);
        const float d2 = dist2(s2x,s2y,s2z,t); mn2 = fminf(mn2,d2);
        const float d3 = dist2(s3x,s3y,s3z,t); mn3 = fminf(mn3,d3);
        const float d4 = dist2(s4x,s4y,s4z,t); mn4 = fminf(mn4,d4);
        const float d5 = dist2(s5x,s5y,s5z,t); mn5 = fminf(mn5,d5);
        const float d6 = dist2(s6x,s6y,s6z,t); mn6 = fminf(mn6,d6);
        const float d7 = dist2(s7x,s7y,s7z,t); mn7 = fminf(mn7,d7);
        const float pm = fminf(fminf(fminf(d0,d1), fminf(d2,d3)),
                               fminf(fminf(d4,d5), fminf(d6,d7)));
        atomicMin(&s_amin[m], __float_as_uint(pm));  // nonneg: uint cmp == float cmp
    }
    atomicMin(&s_bmin[8*g+0], __float_as_uint(mn0));
    atomicMin(&s_bmin[8*g+1], __float_as_uint(mn1));
    atomicMin(&s_bmin[8*g+2], __float_as_uint(mn2));
    atomicMin(&s_bmin[8*g+3], __float_as_uint(mn3));
    atomicMin(&s_bmin[8*g+4], __float_as_uint(mn4));
    atomicMin(&s_bmin[8*g+5], __float_as_uint(mn5));
    atomicMin(&s_bmin[8*g+6], __float_as_uint(mn6));
    atomicMin(&s_bmin[8*g+7], __float_as_uint(mn7));
    __syncthreads();

    float contrib;
    {   // Pass A: mean over m of min_p.
        const uint2 u = *(const uint2*)&s_amin[2*tid];
        contrib = (__uint_as_float(u.x) + __uint_as_float(u.y)) * (1.0f / Mm);
    }
    // Pass B: threads 0..99 own one real p each.
    if (tid < Pp) contrib += 0.2f * __uint_as_float(s_bmin[tid]) * (1.0f / Pp);

    const float tot = breduce256(contrib, red);
    if (tid == 0) {
        per_patch[n] = tot * (1.0f / 1.2f);
        __threadfence();                                   // publish before count
        s_lastflag = (atomicAdd(done_ctr, 1u) == (unsigned)(Nn - 1));
    }
    __syncthreads();
    if (!s_lastflag) return;

    // ---------------- consumer tail: classification losses (one block) -------
    __shared__ unsigned char matched[Bq * Qq];
    __shared__ int s_card[Bq];
    for (int i = tid; i < Bq * Qq; i += 256) matched[i] = 0;
    if (tid < Bq) s_card[tid] = 0;
    __syncthreads();
    for (int i = tid; i < Nn; i += 256) matched[(i >> 7) * Qq + src_idx[i]] = 1;
    __syncthreads();

    float sum_nll = 0.f, sum_wt = 0.f, cnt_ov = 0.f;
    #pragma unroll
    for (int k = 0; k < 8; ++k) {                // k == batch b (Q == 256)
        const int i = tid + (k << 8);
        const float2 l = ((const float2*)logits)[i];
        const int mt = matched[i];
        const float mx  = fmaxf(l.x, l.y);
        const float lse = mx + logf(expf(l.x - mx) + expf(l.y - mx));
        sum_nll += (mt ? 1.0f : 0.1f) * (lse - (mt ? l.x : l.y));
        sum_wt  += mt ? 1.0f : 0.1f;
        const int pred0 = (l.x >= l.y) ? 1 : 0;  // argmax==0 (tie -> first)
        cnt_ov += (pred0 == mt) ? 1.f : 0.f;
        const unsigned long long bal = __ballot(pred0);
        if ((tid & 63) == 0) atomicAdd(&s_card[k], (int)__popcll(bal));
    }
    float cnt_va = 0.f, gsum = 0.f;
    const volatile float* vpp = per_patch;       // cross-XCD: bypass reg caching
    for (int i = tid; i < Nn; i += 256) {
        const float2 l = ((const float2*)logits)[(i >> 7) * Qq + src_idx[i]];
        cnt_va += (l.x >= l.y) ? 1.f : 0.f;
        gsum   += vpp[i];
    }

    const float t_nll = breduce256(sum_nll, red);
    const float t_wt  = breduce256(sum_wt,  red);
    const float t_ov  = breduce256(cnt_ov,  red);
    const float t_va  = breduce256(cnt_va,  red);
    const float t_gs  = breduce256(gsum,    red);

    if (tid == 0) {
        float cerr = 0.f;
        for (int bb = 0; bb < Bq; ++bb) cerr += fabsf((float)s_card[bb] - (float)Tt);
        out[0] = t_nll / t_wt;
        out[1] = 100.f * t_va / (float)Nn;
        out[2] = 100.f * t_ov / (float)(Bq * Qq);
        out[3] = cerr / (float)Bq;
        out[4] = t_gs / (float)Nn;
    }
}

extern "C" void kernel_launch(void* const* d_in, const int* in_sizes, int n_in,
                              void* d_out, int out_size, void* d_ws, size_t ws_size,
                              hipStream_t stream) {
    const float* logits   = (const float*)d_in[0];  // [B,Q,2]
    const float* pred_pts = (const float*)d_in[1];  // [B,Q,P,3]
    const float* tgt_pts  = (const float*)d_in[2];  // [B,T,M,3]
    const int*   src_idx  = (const int*)  d_in[3];  // [B,T]
    float* out       = (float*)d_out;               // 5 scalars
    float* per_patch = (float*)d_ws;                // [1024] floats
    unsigned* ctr    = (unsigned*)((char*)d_ws + 4096);

    hipMemsetAsync(ctr, 0, sizeof(unsigned), stream);   // graph-capture legal
    fused_kernel<<<Nn, 256, 0, stream>>>(logits, pred_pts, tgt_pts, src_idx,
                                         per_patch, ctr, out);
}